// Round 5
// baseline (244.099 us; speedup 1.0000x reference)
//
#include <hip/hip_runtime.h>

// PositionalEncoding: out[b,s,d] = x[b,s,d] + pe[s,d]
//   pe[s,d] = sin(s / 10000^((d/2)/S)) if d even else cos(...)
// x: [B=8, S=4096, D=1024] float32.
//
// R1 lesson: 8-batch loop per thread serialized memory ops -> 2.28 TB/s.
// R2 lesson: __builtin_nontemporal_* needs a clang ext_vector_type.
// R3 lesson: 4-batch/thread (8 x 16MiB strided streams/wave + NT loads)
//   regressed (221.4 -> 229.9). ALU is hidden (~120cy vs 800cy budget).
// R4 lesson: plain vs NT store A/B neutral (220.1 vs 221.4) -> store cache
//   policy is not the gap. Kernel-only ~59us = 4.5 TB/s vs m13 copy 6.29.
// R7 lesson (compile fail): cannot take address of ext_vector element
//   (&v.x) — __sincosf must write scalar locals.
// R7 (this): G11 grid-stride — 2048 blocks x 256 thr, 16 float4/thread,
//   2-deep load pipeline, persistent waves (no WG churn). Stride 512K
//   float4 => s alternates {s0, s0+2048} per thread: pe computed ONCE
//   (2 vectors), inner loop is pure load/add/store.

#define PE_S    4096
#define PE_D    1024
#define N4      (8 * PE_S * PE_D / 4)   // 8,388,608 float4
#define BLOCKS  2048
#define THREADS 256
#define STRIDE  (BLOCKS * THREADS)      // 524,288 float4 per grid sweep
#define ITERS   (N4 / STRIDE)           // 16

typedef float f32x4 __attribute__((ext_vector_type(4)));

__global__ __launch_bounds__(THREADS, 8) void PositionalEncoding_84095459656362_kernel(
    const float* __restrict__ x, float* __restrict__ out) {
    const int i0 = blockIdx.x * THREADS + threadIdx.x;  // float4 index, < STRIDE
    const int d4 = (i0 & (PE_D / 4 - 1)) << 2;          // d base: 0..1020
    const int s0 = i0 >> 8;                             // 0..2047; odd iters use s0+2048

    // angle(k) = s * 10000^(-k/S) = s * exp2(k * c), c = -log2(10000)/4096
    const float c  = -0.0032440703857f;
    const float r1 = 0.99775390625f;                    // 10000^(-1/4096)
    const float e0 = __builtin_exp2f((float)(d4 >> 1) * c);

    const float ae0 = (float)s0 * e0;                   // even iterations (s = s0)
    const float ae1 = ae0 * r1;
    const float ao0 = (float)(s0 + 2048) * e0;          // odd iterations (s = s0+2048)
    const float ao1 = ao0 * r1;

    float sa, ca, sb, cb;
    f32x4 pe0, pe1;                     // (sin a, cos a, sin a*r1, cos a*r1)
    __sincosf(ae0, &sa, &ca);
    __sincosf(ae1, &sb, &cb);
    pe0.x = sa; pe0.y = ca; pe0.z = sb; pe0.w = cb;
    __sincosf(ao0, &sa, &ca);
    __sincosf(ao1, &sb, &cb);
    pe1.x = sa; pe1.y = ca; pe1.z = sb; pe1.w = cb;

    const f32x4* xin = (const f32x4*)x + i0;
    f32x4*       o   = (f32x4*)out     + i0;

    // 2-deep software pipeline: 2 loads in flight per wave at all times.
    f32x4 v0 = xin[0];
    f32x4 v1 = xin[STRIDE];
#pragma unroll
    for (int k = 0; k < ITERS - 2; k += 2) {
        const f32x4 n0 = xin[(k + 2) * STRIDE];
        const f32x4 n1 = xin[(k + 3) * STRIDE];
        o[k * STRIDE]       = v0 + pe0;
        o[(k + 1) * STRIDE] = v1 + pe1;
        v0 = n0;
        v1 = n1;
    }
    o[(ITERS - 2) * STRIDE] = v0 + pe0;
    o[(ITERS - 1) * STRIDE] = v1 + pe1;
}

extern "C" void kernel_launch(void* const* d_in, const int* in_sizes, int n_in,
                              void* d_out, int out_size, void* d_ws, size_t ws_size,
                              hipStream_t stream) {
    const float* x = (const float*)d_in[0];
    float* out = (float*)d_out;
    PositionalEncoding_84095459656362_kernel<<<BLOCKS, THREADS, 0, stream>>>(x, out);
}

// Round 8
// 232.860 us; speedup vs baseline: 1.0483x; 1.0483x over previous
//
#include <hip/hip_runtime.h>

// PositionalEncoding: out[b,s,d] = x[b,s,d] + pe[s,d]
//   pe[s,d] = sin(s / 10000^((d/2)/S)) if d even else cos(...)
// x: [B=8, S=4096, D=1024] float32.
//
// R1 lesson: 8-batch loop/thread, 16-MiB stride -> 2.28 TB/s.
// R2 lesson: __builtin_nontemporal_* needs a clang ext_vector_type.
// R3 lesson: 4-batch straight-line, 16-MiB streams + NT loads -> regressed.
// R4 lesson: plain vs NT store neutral -> store cache policy not the gap.
// R6 lesson: grid-stride 8-MiB stride, 2-deep pipeline -> 92us kernel,
//   2.8 TB/s hierarchy. MLP fix changed nothing vs R1 -> huge pow2 strides
//   are the poison (channel aliasing / row locality), NOT load count.
//   Direct counter model: total = kernel + 152us fixed fills. Flat = 68us.
// R9 lesson (correctness fail, absmax 2.0): s must wrap at PE_S across the
//   8 batch images — sBase needs & (PE_S-1). Block tiles never cross a
//   batch boundary (16 rows, aligned), so masking the base suffices.
// R10 (this): R9 + the one-line mask fix. Block-contiguous tile loop (the
//   fill kernel's own pattern): block owns 64 KiB contiguous, iteration
//   stride 4 KiB, 2-deep pipeline, persistent waves. d4 thread-constant.

#define PE_S    4096
#define PE_D    1024
#define N4      (8 * PE_S * PE_D / 4)   // 8,388,608 float4
#define THREADS 256
#define ITERS   16
#define CHUNK   (THREADS * ITERS)       // 4096 float4 = 64 KiB per block
#define BLOCKS  (N4 / CHUNK)            // 2048

typedef float f32x4 __attribute__((ext_vector_type(4)));

__device__ __forceinline__ f32x4 pe_vec(float a0, float r1) {
    // (sin a0, cos a0, sin a0*r1, cos a0*r1)
    float sa, ca, sb, cb;
    __sincosf(a0, &sa, &ca);
    __sincosf(a0 * r1, &sb, &cb);
    f32x4 p; p.x = sa; p.y = ca; p.z = sb; p.w = cb;
    return p;
}

__global__ __launch_bounds__(THREADS, 8) void PositionalEncoding_84095459656362_kernel(
    const float* __restrict__ x, float* __restrict__ out) {
    const int tid   = threadIdx.x;
    const int base  = blockIdx.x * CHUNK + tid;          // float4 index
    const int d4    = tid << 2;                          // 0..1020, thread-constant
    const int sBase = (base >> 8) & (PE_S - 1);          // s wraps per batch image!

    // angle(k) = s * 10000^(-k/S) = s * exp2(k * c), c = -log2(10000)/4096
    const float c  = -0.0032440703857f;
    const float r1 = 0.99775390625f;                     // 10000^(-1/4096)
    const float e0 = __builtin_exp2f((float)(d4 >> 1) * c);

    const f32x4* xin = (const f32x4*)x + base;
    f32x4*       o   = (f32x4*)out     + base;

    // 2-deep software pipeline over a 64-KiB contiguous block tile.
    f32x4 v0 = xin[0 * THREADS];
    f32x4 v1 = xin[1 * THREADS];
#pragma unroll
    for (int k = 0; k < ITERS - 2; k += 2) {
        const f32x4 n0 = xin[(k + 2) * THREADS];
        const f32x4 n1 = xin[(k + 3) * THREADS];
        o[k * THREADS]       = v0 + pe_vec((float)(sBase + k)     * e0, r1);
        o[(k + 1) * THREADS] = v1 + pe_vec((float)(sBase + k + 1) * e0, r1);
        v0 = n0;
        v1 = n1;
    }
    o[(ITERS - 2) * THREADS] = v0 + pe_vec((float)(sBase + ITERS - 2) * e0, r1);
    o[(ITERS - 1) * THREADS] = v1 + pe_vec((float)(sBase + ITERS - 1) * e0, r1);
}

extern "C" void kernel_launch(void* const* d_in, const int* in_sizes, int n_in,
                              void* d_out, int out_size, void* d_ws, size_t ws_size,
                              hipStream_t stream) {
    const float* x = (const float*)d_in[0];
    float* out = (float*)d_out;
    PositionalEncoding_84095459656362_kernel<<<BLOCKS, THREADS, 0, stream>>>(x, out);
}

// Round 9
// 226.941 us; speedup vs baseline: 1.0756x; 1.0261x over previous
//
#include <hip/hip_runtime.h>

// PositionalEncoding: out[b,s,d] = x[b,s,d] + pe[s,d]
//   pe[s,d] = sin(s / 10000^((d/2)/S)) if d even else cos(...)
// x: [B=8, S=4096, D=1024] float32.
//
// Counter-established model: dur_us = kernel + ~150us fixed harness fills.
// R1  lesson: 8-batch loop/thread, 16-MiB stride -> 2.28 TB/s.
// R3  lesson: straight-line 4 loads at 16-MiB strides -> regressed.
// R4  lesson: NT vs plain store neutral. Flat 1-float4/thread ~= 68us.
// R6  lesson: grid-stride loop (8-MiB stride) -> 92us kernel, occ 48%,
//   VALUBusy 2%, FETCH 64MB (L3 covers half of x), WRITE 128MB.
// R10 lesson: block-contiguous loop (4-KiB stride) -> 84us. Stride nearly
//   irrelevant -> channel-aliasing theory dead; per-thread LOOPS lose to
//   straight-line flat, period. ALU/MLP/occupancy all ruled out.
// R11 (this): flat straight-line, 2 ADJACENT float4 per thread (32B/lane,
//   4-KiB contiguous burst per wave, half the wave churn, 2 independent
//   adjacent loads in flight). Last flat knob: payload per wave.
//   Predict kernel 68 -> 50-57us; if neutral -> flat-16B was the floor.

#define PE_S    4096
#define PE_D    1024
#define NPAIR   (8 * PE_S * PE_D / 8)   // 4,194,304 float4-pairs
#define THREADS 256
#define BLOCKS  (NPAIR / THREADS)       // 16384

typedef float f32x4 __attribute__((ext_vector_type(4)));

__global__ __launch_bounds__(THREADS) void PositionalEncoding_84095459656362_kernel(
    const float* __restrict__ x, float* __restrict__ out) {
    const int j  = blockIdx.x * THREADS + threadIdx.x;  // pair index
    const int i0 = j << 1;                              // float4 index
    // float4 i0 covers d = 8*(j&127) + {0..3}; pair stays in one s-row.
    const int kb = (j & 127) << 2;                      // k base = 4*(j&127)
    const int s  = (j >> 7) & (PE_S - 1);               // s wraps per batch image

    // angle(k) = s * 10000^(-k/S) = s * exp2(k*c), c = -log2(10000)/4096
    const float c  = -0.0032440703857f;
    const float r1 = 0.99775390625f;                    // 10000^(-1/4096)
    const float a0 = (float)s * __builtin_exp2f((float)kb * c);
    const float a1 = a0 * r1;
    const float a2 = a1 * r1;
    const float a3 = a2 * r1;

    float s0, c0, s1, c1, s2, c2, s3, c3;
    __sincosf(a0, &s0, &c0);   // d = 8m+0 (sin), 8m+1 (cos)
    __sincosf(a1, &s1, &c1);   // d = 8m+2, 8m+3
    __sincosf(a2, &s2, &c2);   // d = 8m+4, 8m+5
    __sincosf(a3, &s3, &c3);   // d = 8m+6, 8m+7

    // Two independent adjacent 16B loads in flight, then two stores.
    const f32x4 v0 = ((const f32x4*)x)[i0];
    const f32x4 v1 = ((const f32x4*)x)[i0 + 1];
    f32x4 r0, r1v;
    r0.x  = v0.x + s0; r0.y  = v0.y + c0; r0.z  = v0.z + s1; r0.w  = v0.w + c1;
    r1v.x = v1.x + s2; r1v.y = v1.y + c2; r1v.z = v1.z + s3; r1v.w = v1.w + c3;
    ((f32x4*)out)[i0]     = r0;
    ((f32x4*)out)[i0 + 1] = r1v;
}

extern "C" void kernel_launch(void* const* d_in, const int* in_sizes, int n_in,
                              void* d_out, int out_size, void* d_ws, size_t ws_size,
                              hipStream_t stream) {
    const float* x = (const float*)d_in[0];
    float* out = (float*)d_out;
    PositionalEncoding_84095459656362_kernel<<<BLOCKS, THREADS, 0, stream>>>(x, out);
}

// Round 10
// 217.022 us; speedup vs baseline: 1.1248x; 1.0457x over previous
//
#include <hip/hip_runtime.h>

// PositionalEncoding: out[b,s,d] = x[b,s,d] + pe[s,d]
//   pe[s,d] = sin(s / 10000^((d/2)/S)) if d even else cos(...)
// x: [B=8, S=4096, D=1024] float32.
//
// Counter-established model: dur_us = kernel + ~150us fixed harness fills.
// Knob matrix on the ~70us flat kernel (all neutral or worse):
//   R1/R6/R10: per-thread loops (16MiB/8MiB/4KiB stride) -> 92/84us. Loops
//     always lose to straight-line flat; stride nearly irrelevant.
//   R3: straight-line 4x 16-MiB-strided loads + NT loads -> worse.
//   R4: NT store alone -> neutral (220.1).
//   R11: 2 adjacent float4/thread -> slightly worse (~77us kernel).
//   Little's law vs measured R10 counters: in-flight >> observed read BW
//     -> memory system plateaus ~3.7 TB/s for this mix, not issue-limited.
// R12 (this): last mechanism-backed knob. Working set (128+128 MB) == L3
//   (256 MB); FETCH=64MB proves L3 half-caches x while out stores thrash
//   it. NT on BOTH streams -> bypass L3, two clean HBM streams.
//   Predict: FETCH 64->128MB; kernel 70->50-55 if L3 churn was the cost;
//   if neutral/worse -> roofline (all structures+policies at same plateau).

#define PE_S 4096
#define PE_D 1024
#define N4   (8 * PE_S * PE_D / 4)   // 8,388,608 float4 elements

typedef float f32x4 __attribute__((ext_vector_type(4)));

__global__ __launch_bounds__(256) void PositionalEncoding_84095459656362_kernel(
    const float* __restrict__ x, float* __restrict__ out) {
    const int i  = blockIdx.x * blockDim.x + threadIdx.x;   // float4 index
    const int d4 = (i & (PE_D / 4 - 1)) << 2;               // d base: 0..1020
    const int s  = (i >> 8) & (PE_S - 1);                   // sequence pos

    // angle(k) = s * 10000^(-k/S) = s * exp2(k * c), c = -log2(10000)/4096
    const float c   = -0.0032440703857f;
    const float r1  = 0.99775390625f;                        // 10000^(-1/4096)
    const float e0  = __builtin_exp2f((float)(d4 >> 1) * c);
    const float a0  = (float)s * e0;
    const float a1  = a0 * r1;

    float s0, c0, s1, c1;
    __sincosf(a0, &s0, &c0);   // d even -> sin, d odd -> cos
    __sincosf(a1, &s1, &c1);

    const f32x4 v = __builtin_nontemporal_load(&((const f32x4*)x)[i]);
    f32x4 r;
    r.x = v.x + s0;
    r.y = v.y + c0;
    r.z = v.z + s1;
    r.w = v.w + c1;
    __builtin_nontemporal_store(r, &((f32x4*)out)[i]);
}

extern "C" void kernel_launch(void* const* d_in, const int* in_sizes, int n_in,
                              void* d_out, int out_size, void* d_ws, size_t ws_size,
                              hipStream_t stream) {
    const float* x = (const float*)d_in[0];
    float* out = (float*)d_out;
    PositionalEncoding_84095459656362_kernel<<<N4 / 256, 256, 0, stream>>>(x, out);
}